// Round 1
// baseline (877.992 us; speedup 1.0000x reference)
//
#include <hip/hip_runtime.h>
#include <cstdint>

#define NPX 2304      // 48*48
#define MM 6912       // 3*2304
#define NW 108        // MM/64
#define TOPK 2000
#define NEGV -1000000000.0f
#define OBJ_THRF 0.3f
#define IOU_THRF 0.7f
#define IMGF 768.0f

typedef unsigned long long u64;
typedef unsigned int u32;

__device__ __forceinline__ u64 shfl64(u64 v, int src) {
  int lo = __shfl((int)(v & 0xffffffffull), src, 64);
  int hi = __shfl((int)(v >> 32), src, 64);
  return ((u64)(u32)hi << 32) | (u32)lo;
}

// ---------------- conv 3x3, 256->256, fp32 ----------------
// grid (4 oc-tiles, 48 rows, 2 k-splits), block 256
// thread: 4 oc x 3 px; x + w staged in LDS; w reads as float2 pairs (stride-66
// padding keeps staging writes ~conflict-free while float2 stays 8B-aligned)
__global__ __launch_bounds__(256) void k_conv(const float* __restrict__ x,
                                              const float* __restrict__ cw,
                                              float* __restrict__ interp) {
  __shared__ float xs[16 * 3 * 50];    // [ic][row][col+1], zero-padded halo
  __shared__ float wl[144 * 66];       // [it = ic*9+tap][oc], stride 66
  const int tid = threadIdx.x;
  const int og = tid & 15;             // oc group: oc = oc0 + og*4 + kk
  const int pg = tid >> 4;             // px group: px = 3*pg + p
  const int oc0 = blockIdx.x * 64;
  const int h = blockIdx.y;
  const int ks = blockIdx.z;

  float acc[4][3];
#pragma unroll
  for (int i = 0; i < 4; i++)
#pragma unroll
    for (int j = 0; j < 3; j++) acc[i][j] = 0.f;

  for (int icc = 0; icc < 8; ++icc) {
    const int ic0 = ks * 128 + icc * 16;
    // stage x: 16 ic x 3 rows x 50 cols (halo, zero pad)
    for (int e = tid; e < 2400; e += 256) {
      int ic = e / 150, rem = e % 150;
      int r = rem / 50, col = rem % 50 - 1;
      int gr = h - 1 + r;
      float v = 0.f;
      if (col >= 0 && col < 48 && gr >= 0 && gr < 48)
        v = x[(ic0 + ic) * NPX + gr * 48 + col];
      xs[e] = v;  // e == (ic*3+r)*50 + (col+1)
    }
    // stage w: 64 oc x 144 (ic16 x 9 taps), coalesced global reads
    for (int e = tid; e < 9216; e += 256) {
      int oc = e / 144, it = e % 144;
      wl[it * 66 + oc] = cw[(oc0 + oc) * 2304 + ic0 * 9 + it];
    }
    __syncthreads();
#pragma unroll
    for (int ic = 0; ic < 16; ++ic) {
      float xr[3][5];
#pragma unroll
      for (int r = 0; r < 3; r++)
#pragma unroll
        for (int q = 0; q < 5; q++)
          xr[r][q] = xs[(ic * 3 + r) * 50 + 3 * pg + q];
#pragma unroll
      for (int r = 0; r < 3; r++)
#pragma unroll
        for (int dxk = 0; dxk < 3; dxk++) {
          int it = ic * 9 + r * 3 + dxk;
          const float2 w01 = *(const float2*)&wl[it * 66 + og * 4];
          const float2 w23 = *(const float2*)&wl[it * 66 + og * 4 + 2];
          float wv[4] = {w01.x, w01.y, w23.x, w23.y};
#pragma unroll
          for (int p = 0; p < 3; p++) {
            float xv = xr[r][p + dxk];
#pragma unroll
            for (int kk = 0; kk < 4; kk++) acc[kk][p] += wv[kk] * xv;
          }
        }
    }
    __syncthreads();
  }
#pragma unroll
  for (int kk = 0; kk < 4; kk++) {
    int oc = oc0 + og * 4 + kk;
#pragma unroll
    for (int p = 0; p < 3; p++)
      interp[ks * (256 * NPX) + oc * NPX + h * 48 + 3 * pg + p] = acc[kk][p];
  }
}

// ---------------- heads + anchor decode ----------------
// grid 9, block 256; one thread per pixel, 15 head outputs accumulated over c
__global__ __launch_bounds__(256) void k_decode(const float* __restrict__ interp,
                                                const float* __restrict__ cb,
                                                const float* __restrict__ dw,
                                                const float* __restrict__ db,
                                                const float* __restrict__ rw,
                                                const float* __restrict__ rb,
                                                const float* __restrict__ anch,
                                                float* __restrict__ s,
                                                float4* __restrict__ boxes) {
  __shared__ float wl[256 * 16];
  const int tid = threadIdx.x;
  const int p = blockIdx.x * 256 + tid;
  for (int e = tid; e < 3840; e += 256) {
    int o = e % 15, c = e / 15;
    wl[c * 16 + o] = (o < 3) ? dw[o * 256 + c] : rw[(o - 3) * 256 + c];
  }
  __syncthreads();
  float acc[15];
#pragma unroll
  for (int o = 0; o < 15; o++) acc[o] = 0.f;
  const float* p0 = interp;
  const float* p1 = interp + 256 * NPX;
  for (int c = 0; c < 256; ++c) {
    float v = p0[c * NPX + p] + p1[c * NPX + p] + cb[c];
#pragma unroll
    for (int o = 0; o < 15; o++) acc[o] += v * wl[c * 16 + o];
  }
  const float4* an4 = (const float4*)anch;
#pragma unroll
  for (int a = 0; a < 3; ++a) {
    int m = a * NPX + p;
    float logit = acc[a] + db[a];
    float score = 1.f / (1.f + expf(-logit));
    float dxv = acc[3 + 0 + a] + rb[0 + a];
    float dyv = acc[3 + 3 + a] + rb[3 + a];
    float dwv = acc[3 + 6 + a] + rb[6 + a];
    float dhv = acc[3 + 9 + a] + rb[9 + a];
    float4 an = an4[m];
    float aw = an.z - an.x;
    float ah = an.w - an.y;
    float acx = an.y + aw * 0.5f;  // NOTE: intentionally swapped (reference quirk)
    float acy = an.x + ah * 0.5f;  // NOTE: intentionally swapped (reference quirk)
    float pxc = acx + dxv * aw;
    float pyc = acy + dyv * ah;
    float pw = aw * expf(dwv);
    float ph = ah * expf(dhv);
    float b0 = pxc - pw * 0.5f, b1 = pyc - ph * 0.5f;
    float b2 = pxc + pw * 0.5f, b3 = pyc + ph * 0.5f;
    b0 = fminf(fmaxf(b0, 0.f), IMGF);
    b1 = fminf(fmaxf(b1, 0.f), IMGF);
    b2 = fminf(fmaxf(b2, 0.f), IMGF);
    b3 = fminf(fmaxf(b3, 0.f), IMGF);
    float hts = b2 - b0, wds = b3 - b1;
    bool valid = (hts > 0.f) && (wds > 0.f) && (score > OBJ_THRF);
    s[m] = valid ? score : NEGV;
    boxes[m] = make_float4(b0, b1, b2, b3);
  }
}

// ---------------- stable sort (desc score, asc idx) ----------------
// single block 1024 threads, bitonic over 8192 padded (u32 key, u16 idx)
__global__ __launch_bounds__(1024) void k_sort(const float* __restrict__ s,
                                               const float4* __restrict__ boxes,
                                               float* __restrict__ ssc,
                                               float4* __restrict__ sboxes) {
  __shared__ u32 ks_[8192];
  __shared__ unsigned short id_[8192];
  const int tid = threadIdx.x;
  for (int i = tid; i < 8192; i += 1024) {
    u32 k;
    if (i < MM) {
      u32 u = __float_as_uint(s[i]);
      u = u ^ (u32)(((int)u >> 31) | 0x80000000);
      k = ~u;  // ascending k == descending score
    } else {
      k = 0xFFFFFFFFu;  // pad sorts last
    }
    ks_[i] = k;
    id_[i] = (unsigned short)i;
  }
  for (u32 kk = 2; kk <= 8192; kk <<= 1) {
    for (u32 j = kk >> 1; j > 0; j >>= 1) {
      __syncthreads();
      for (int i = tid; i < 8192; i += 1024) {
        int l = i ^ (int)j;
        if (l > i) {
          u32 ka = ks_[i], kb = ks_[l];
          unsigned short ia = id_[i], ib = id_[l];
          bool up = ((i & (int)kk) == 0);
          bool gt = (ka > kb) || (ka == kb && ia > ib);
          if (gt == up) { ks_[i] = kb; ks_[l] = ka; id_[i] = ib; id_[l] = ia; }
        }
      }
    }
  }
  __syncthreads();
  for (int i = tid; i < MM; i += 1024) {
    int m = id_[i];
    ssc[i] = s[m];
    sboxes[i] = boxes[m];
  }
}

// ---------------- IOU suppression bit-matrix ----------------
// grid (108 row-tiles, 27 word-groups), block 256 (4 waves = 4 words)
__global__ __launch_bounds__(256) void k_mask(const float4* __restrict__ sboxes,
                                              u64* __restrict__ mask) {
  const int rt = blockIdx.x;
  const int w = blockIdx.y * 4 + (threadIdx.x >> 6);
  if (w < rt) return;  // only need cols j in words >= diagonal word
  const int lane = threadIdx.x & 63;
  float4 c = sboxes[w * 64 + lane];
  float areaC = (c.z - c.x) * (c.w - c.y);
  u64 myw = 0;
  for (int r = 0; r < 64; ++r) {
    float4 b = sboxes[rt * 64 + r];
    float iw = fmaxf(fminf(b.z, c.z) - fmaxf(b.x, c.x), 0.f);
    float ih = fmaxf(fminf(b.w, c.w) - fmaxf(b.y, c.y), 0.f);
    float inter = iw * ih;
    float areaB = (b.z - b.x) * (b.w - b.y);
    float un = fmaxf(areaB + areaC - inter, 1e-9f);
    bool bit = (inter / un) > IOU_THRF;
    u64 bal = __ballot(bit);
    if (lane == r) myw = bal;
  }
  mask[(u64)(rt * 64 + lane) * NW + w] = myw;
}

// ---------------- serial NMS scan + output ----------------
// single block 256 threads; chunked by 64 rows; wave-parallel intra-chunk
__global__ __launch_bounds__(256) void k_scan(const u64* __restrict__ mask,
                                              const float* __restrict__ ssc,
                                              const float4* __restrict__ sboxes,
                                              float* __restrict__ out) {
  __shared__ u64 remv[NW];
  __shared__ u64 keepw[NW];
  __shared__ int blist[64];
  __shared__ int nkS;
  __shared__ int kcntS;
  __shared__ int pref[NW];
  const int tid = threadIdx.x;
  if (tid < NW) { remv[tid] = 0; keepw[tid] = 0; }
  if (tid == 0) kcntS = 0;
  __syncthreads();

  for (int c = 0; c < NW; ++c) {
    if (tid < 64) {  // wave 0
      int row = c * 64 + tid;
      u64 dg = mask[(u64)row * NW + c];   // lane's diagonal-block word
      float sv = ssc[row];
      u64 vb = __ballot(sv > OBJ_THRF);   // validity (s==NEG iff invalid)
      u64 w = remv[c];
      u64 kb = 0;
      u64 rem = vb & ~w;
      while (rem) {
        int b = __ffsll(rem) - 1;
        kb |= (1ull << b);
        w |= shfl64(dg, b);  // diag bit b is set (iou(self)=1), so b leaves rem
        rem = vb & ~w;
      }
      int below = __popcll(kb & ((1ull << tid) - 1ull));
      if ((kb >> tid) & 1ull) blist[below] = tid;
      if (tid == 0) {
        keepw[c] = kb;
        nkS = __popcll(kb);
        kcntS += __popcll(kb);
      }
    }
    __syncthreads();
    int nk = nkS;
    // propagate newly-kept rows' suppression to remaining words (4 thr/word)
    for (int wi = c + 1 + (tid >> 2); wi < NW; wi += 64) {
      u64 acc = 0;
      for (int t = (tid & 3); t < nk; t += 4)
        acc |= mask[(u64)(c * 64 + blist[t]) * NW + wi];
      if (acc) atomicOr(&remv[wi], acc);
    }
    __syncthreads();
    if (kcntS >= TOPK) break;  // only top-2000 kept are ever output
  }

  if (tid == 0) {
    int run = 0;
    for (int cc = 0; cc < NW; ++cc) { pref[cc] = run; run += __popcll(keepw[cc]); }
  }
  __syncthreads();
  // defaults: scores -1, boxes 0
  for (int e = tid; e < TOPK * 5; e += 256) out[e] = (e < TOPK) ? -1.0f : 0.0f;
  __syncthreads();
  float4* ob = (float4*)(out + TOPK);
  for (int i = tid; i < MM; i += 256) {
    int cc = i >> 6, b = i & 63;
    u64 kb = keepw[cc];
    if ((kb >> b) & 1ull) {
      int rank = pref[cc] + __popcll(kb & ((1ull << b) - 1ull));
      if (rank < TOPK) {
        out[rank] = ssc[i];
        ob[rank] = sboxes[i];
      }
    }
  }
}

extern "C" void kernel_launch(void* const* d_in, const int* in_sizes, int n_in,
                              void* d_out, int out_size, void* d_ws, size_t ws_size,
                              hipStream_t stream) {
  const float* x  = (const float*)d_in[0];
  const float* cw = (const float*)d_in[1];
  const float* cb = (const float*)d_in[2];
  const float* dw = (const float*)d_in[3];
  const float* db = (const float*)d_in[4];
  const float* rw = (const float*)d_in[5];
  const float* rb = (const float*)d_in[6];
  const float* an = (const float*)d_in[7];
  char* ws = (char*)d_ws;
  float*  interp = (float*)(ws);                 // 2 * 256 * 2304 * 4 = 4,718,592 B
  float*  s      = (float*)(ws + 4718592);       // 27,648 B
  float4* boxes  = (float4*)(ws + 4746240);      // 110,592 B
  float*  ssc    = (float*)(ws + 4856832);       // 27,648 B
  float4* sboxes = (float4*)(ws + 4884480);      // 110,592 B
  u64*    mask   = (u64*)(ws + 4995072);         // 6912*108*8 = 5,971,968 B
  float* out = (float*)d_out;

  hipLaunchKernelGGL(k_conv, dim3(4, 48, 2), dim3(256), 0, stream, x, cw, interp);
  hipLaunchKernelGGL(k_decode, dim3(9), dim3(256), 0, stream, interp, cb, dw, db, rw, rb, an, s, boxes);
  hipLaunchKernelGGL(k_sort, dim3(1), dim3(1024), 0, stream, s, boxes, ssc, sboxes);
  hipLaunchKernelGGL(k_mask, dim3(108, 27), dim3(256), 0, stream, sboxes, mask);
  hipLaunchKernelGGL(k_scan, dim3(1), dim3(256), 0, stream, mask, ssc, sboxes, out);
}

// Round 2
// 450.868 us; speedup vs baseline: 1.9473x; 1.9473x over previous
//
#include <hip/hip_runtime.h>
#include <cstdint>

#define NPX 2304      // 48*48
#define MM 6912       // 3*2304
#define NW 108        // MM/64
#define TOPK 2000
#define NEGV -1000000000.0f
#define OBJ_THRF 0.3f
#define IOU_THRF 0.7f
#define IMGF 768.0f

typedef unsigned long long u64;
typedef unsigned int u32;

__device__ __forceinline__ u64 shfl64(u64 v, int src) {
  int lo = __shfl((int)(v & 0xffffffffull), src, 64);
  int hi = __shfl((int)(v >> 32), src, 64);
  return ((u64)(u32)hi << 32) | (u32)lo;
}

// ---------------- conv 3x3, 256->256, fp32 ----------------
__global__ __launch_bounds__(256) void k_conv(const float* __restrict__ x,
                                              const float* __restrict__ cw,
                                              float* __restrict__ interp) {
  __shared__ float xs[16 * 3 * 50];    // [ic][row][col+1], zero-padded halo
  __shared__ float wl[144 * 66];       // [it = ic*9+tap][oc], stride 66
  const int tid = threadIdx.x;
  const int og = tid & 15;             // oc group: oc = oc0 + og*4 + kk
  const int pg = tid >> 4;             // px group: px = 3*pg + p
  const int oc0 = blockIdx.x * 64;
  const int h = blockIdx.y;
  const int ks = blockIdx.z;

  float acc[4][3];
#pragma unroll
  for (int i = 0; i < 4; i++)
#pragma unroll
    for (int j = 0; j < 3; j++) acc[i][j] = 0.f;

  for (int icc = 0; icc < 8; ++icc) {
    const int ic0 = ks * 128 + icc * 16;
    for (int e = tid; e < 2400; e += 256) {
      int ic = e / 150, rem = e % 150;
      int r = rem / 50, col = rem % 50 - 1;
      int gr = h - 1 + r;
      float v = 0.f;
      if (col >= 0 && col < 48 && gr >= 0 && gr < 48)
        v = x[(ic0 + ic) * NPX + gr * 48 + col];
      xs[e] = v;
    }
    for (int e = tid; e < 9216; e += 256) {
      int oc = e / 144, it = e % 144;
      wl[it * 66 + oc] = cw[(oc0 + oc) * 2304 + ic0 * 9 + it];
    }
    __syncthreads();
#pragma unroll
    for (int ic = 0; ic < 16; ++ic) {
      float xr[3][5];
#pragma unroll
      for (int r = 0; r < 3; r++)
#pragma unroll
        for (int q = 0; q < 5; q++)
          xr[r][q] = xs[(ic * 3 + r) * 50 + 3 * pg + q];
#pragma unroll
      for (int r = 0; r < 3; r++)
#pragma unroll
        for (int dxk = 0; dxk < 3; dxk++) {
          int it = ic * 9 + r * 3 + dxk;
          const float2 w01 = *(const float2*)&wl[it * 66 + og * 4];
          const float2 w23 = *(const float2*)&wl[it * 66 + og * 4 + 2];
          float wv[4] = {w01.x, w01.y, w23.x, w23.y};
#pragma unroll
          for (int p = 0; p < 3; p++) {
            float xv = xr[r][p + dxk];
#pragma unroll
            for (int kk = 0; kk < 4; kk++) acc[kk][p] += wv[kk] * xv;
          }
        }
    }
    __syncthreads();
  }
#pragma unroll
  for (int kk = 0; kk < 4; kk++) {
    int oc = oc0 + og * 4 + kk;
#pragma unroll
    for (int p = 0; p < 3; p++)
      interp[ks * (256 * NPX) + oc * NPX + h * 48 + 3 * pg + p] = acc[kk][p];
  }
}

// ---------------- heads + anchor decode ----------------
__global__ __launch_bounds__(256) void k_decode(const float* __restrict__ interp,
                                                const float* __restrict__ cb,
                                                const float* __restrict__ dw,
                                                const float* __restrict__ db,
                                                const float* __restrict__ rw,
                                                const float* __restrict__ rb,
                                                const float* __restrict__ anch,
                                                float* __restrict__ s,
                                                float4* __restrict__ boxes) {
  __shared__ float wl[256 * 16];
  const int tid = threadIdx.x;
  const int p = blockIdx.x * 256 + tid;
  for (int e = tid; e < 3840; e += 256) {
    int o = e % 15, c = e / 15;
    wl[c * 16 + o] = (o < 3) ? dw[o * 256 + c] : rw[(o - 3) * 256 + c];
  }
  __syncthreads();
  float acc[15];
#pragma unroll
  for (int o = 0; o < 15; o++) acc[o] = 0.f;
  const float* p0 = interp;
  const float* p1 = interp + 256 * NPX;
  for (int c = 0; c < 256; ++c) {
    float v = p0[c * NPX + p] + p1[c * NPX + p] + cb[c];
#pragma unroll
    for (int o = 0; o < 15; o++) acc[o] += v * wl[c * 16 + o];
  }
  const float4* an4 = (const float4*)anch;
#pragma unroll
  for (int a = 0; a < 3; ++a) {
    int m = a * NPX + p;
    float logit = acc[a] + db[a];
    float score = 1.f / (1.f + expf(-logit));
    float dxv = acc[3 + 0 + a] + rb[0 + a];
    float dyv = acc[3 + 3 + a] + rb[3 + a];
    float dwv = acc[3 + 6 + a] + rb[6 + a];
    float dhv = acc[3 + 9 + a] + rb[9 + a];
    float4 an = an4[m];
    float aw = an.z - an.x;
    float ah = an.w - an.y;
    float acx = an.y + aw * 0.5f;  // NOTE: intentionally swapped (reference quirk)
    float acy = an.x + ah * 0.5f;  // NOTE: intentionally swapped (reference quirk)
    float pxc = acx + dxv * aw;
    float pyc = acy + dyv * ah;
    float pw = aw * expf(dwv);
    float ph = ah * expf(dhv);
    float b0 = pxc - pw * 0.5f, b1 = pyc - ph * 0.5f;
    float b2 = pxc + pw * 0.5f, b3 = pyc + ph * 0.5f;
    b0 = fminf(fmaxf(b0, 0.f), IMGF);
    b1 = fminf(fmaxf(b1, 0.f), IMGF);
    b2 = fminf(fmaxf(b2, 0.f), IMGF);
    b3 = fminf(fmaxf(b3, 0.f), IMGF);
    float hts = b2 - b0, wds = b3 - b1;
    bool valid = (hts > 0.f) && (wds > 0.f) && (score > OBJ_THRF);
    s[m] = valid ? score : NEGV;
    boxes[m] = make_float4(b0, b1, b2, b3);
  }
}

// ---------------- stable sort (desc score, asc idx) ----------------
__global__ __launch_bounds__(1024) void k_sort(const float* __restrict__ s,
                                               const float4* __restrict__ boxes,
                                               float* __restrict__ ssc,
                                               float4* __restrict__ sboxes) {
  __shared__ u32 ks_[8192];
  __shared__ unsigned short id_[8192];
  const int tid = threadIdx.x;
  for (int i = tid; i < 8192; i += 1024) {
    u32 k;
    if (i < MM) {
      u32 u = __float_as_uint(s[i]);
      u = u ^ (u32)(((int)u >> 31) | 0x80000000);
      k = ~u;  // ascending k == descending score
    } else {
      k = 0xFFFFFFFFu;  // pad sorts last
    }
    ks_[i] = k;
    id_[i] = (unsigned short)i;
  }
  for (u32 kk = 2; kk <= 8192; kk <<= 1) {
    for (u32 j = kk >> 1; j > 0; j >>= 1) {
      __syncthreads();
      for (int i = tid; i < 8192; i += 1024) {
        int l = i ^ (int)j;
        if (l > i) {
          u32 ka = ks_[i], kb = ks_[l];
          unsigned short ia = id_[i], ib = id_[l];
          bool up = ((i & (int)kk) == 0);
          bool gt = (ka > kb) || (ka == kb && ia > ib);
          if (gt == up) { ks_[i] = kb; ks_[l] = ka; id_[i] = ib; id_[l] = ia; }
        }
      }
    }
  }
  __syncthreads();
  for (int i = tid; i < MM; i += 1024) {
    int m = id_[i];
    ssc[i] = s[m];
    sboxes[i] = boxes[m];
  }
}

// ---------------- zero-init nz bitmaps ----------------
__global__ __launch_bounds__(256) void k_zero(u64* __restrict__ nz) {
  int i = blockIdx.x * 256 + threadIdx.x;
  if (i < MM * 2) nz[i] = 0;
}

// ---------------- IOU suppression bit-matrix (transposed) ----------------
// mask_t[w*MM + row] = 64 column-bits (cols w*64..w*64+63) of `row`'s IOU>thr
// nz[row*2 + {0,1}]  = bitmap of nonzero words for `row` (w >= row's chunk)
__global__ __launch_bounds__(256) void k_mask(const float4* __restrict__ sboxes,
                                              u64* __restrict__ mask_t,
                                              u64* __restrict__ nz) {
  __shared__ float4 rb_[64];
  const int rt = blockIdx.x;
  const int w = blockIdx.y * 4 + (threadIdx.x >> 6);
  const int lane = threadIdx.x & 63;
  if (threadIdx.x < 64) rb_[threadIdx.x] = sboxes[rt * 64 + threadIdx.x];
  __syncthreads();
  if (w < rt) return;  // only words >= diagonal are ever read
  float4 c = sboxes[w * 64 + lane];
  float areaC = (c.z - c.x) * (c.w - c.y);
  u64 myw = 0;
  for (int r = 0; r < 64; ++r) {
    float4 b = rb_[r];
    float iw = fmaxf(fminf(b.z, c.z) - fmaxf(b.x, c.x), 0.f);
    float ih = fmaxf(fminf(b.w, c.w) - fmaxf(b.y, c.y), 0.f);
    float inter = iw * ih;
    float areaB = (b.z - b.x) * (b.w - b.y);
    float un = fmaxf(areaB + areaC - inter, 1e-9f);
    bool bit = (inter / un) > IOU_THRF;
    u64 bal = __ballot(bit);
    if (lane == r) myw = bal;  // lane r holds row rt*64+r's word for word w
  }
  mask_t[(size_t)w * MM + rt * 64 + lane] = myw;  // coalesced
  if (myw) atomicOr(&nz[(rt * 64 + lane) * 2 + (w >> 6)], 1ull << (w & 63));
}

// ---------------- serial NMS scan + output ----------------
// per 64-row chunk: coalesced diag load; ballot fast-path when no candidate
// suppresses a later candidate (common: IOU>0.7 is rare); sparse propagation
// via per-row nonzero-word bitmaps. Early exit at TOPK kept.
__global__ __launch_bounds__(256) void k_scan(const u64* __restrict__ mask_t,
                                              const u64* __restrict__ nz,
                                              const float* __restrict__ ssc,
                                              const float4* __restrict__ sboxes,
                                              float* __restrict__ out) {
  __shared__ u64 remv[NW];
  __shared__ u64 keepw[NW];
  __shared__ int blist[64];
  __shared__ int nkS;
  __shared__ int kcntS;
  __shared__ int pref[NW];
  const int tid = threadIdx.x;
  if (tid < NW) { remv[tid] = 0; keepw[tid] = 0; }
  if (tid == 0) kcntS = 0;
  __syncthreads();

  for (int c = 0; c < NW; ++c) {
    if (tid < 64) {  // wave 0
      const int lane = tid;
      u64 dg = mask_t[(size_t)c * MM + c * 64 + lane];  // coalesced 512B
      float sv = ssc[c * 64 + lane];
      u64 vb = __ballot(sv > OBJ_THRF);
      u64 w0 = remv[c];
      u64 cand = vb & ~w0;
      u64 above = (lane < 63) ? ~((2ull << lane) - 1ull) : 0ull;
      bool inC = ((cand >> lane) & 1ull) != 0;
      u64 conf = __ballot(inC && ((dg & above & cand) != 0ull));
      u64 kb;
      if (conf == 0ull) {
        kb = cand;  // fast path: no intra-chunk suppression among candidates
      } else {
        u64 w = w0;
        kb = 0;
        u64 rem = cand;
        while (rem) {
          int b = __ffsll(rem) - 1;
          kb |= (1ull << b);
          w |= shfl64(dg, b);
          rem = vb & ~w;
        }
      }
      int below = __popcll(kb & ((1ull << lane) - 1ull));
      if ((kb >> lane) & 1ull) blist[below] = lane;
      if (lane == 0) {
        keepw[c] = kb;
        nkS = __popcll(kb);
        kcntS += __popcll(kb);
      }
    }
    __syncthreads();
    int nk = nkS;
    if (tid < nk) {  // sparse propagation: only nonzero words > c
      int row = c * 64 + blist[tid];
      u64 nz0 = nz[row * 2], nz1 = nz[row * 2 + 1];
      if (c < 64) {
        nz0 &= (c < 63) ? ~((2ull << c) - 1ull) : 0ull;
      } else {
        nz0 = 0;
        int cc = c - 64;
        nz1 &= ~((2ull << cc) - 1ull);
      }
      while (nz0) {
        int wv = __ffsll(nz0) - 1; nz0 &= nz0 - 1;
        atomicOr(&remv[wv], mask_t[(size_t)wv * MM + row]);
      }
      while (nz1) {
        int wv = __ffsll(nz1) - 1; nz1 &= nz1 - 1;
        atomicOr(&remv[wv + 64], mask_t[(size_t)(wv + 64) * MM + row]);
      }
    }
    __syncthreads();
    if (kcntS >= TOPK) break;  // only top-2000 kept are ever output
  }

  if (tid == 0) {
    int run = 0;
    for (int cc = 0; cc < NW; ++cc) { pref[cc] = run; run += __popcll(keepw[cc]); }
  }
  __syncthreads();
  for (int e = tid; e < TOPK * 5; e += 256) out[e] = (e < TOPK) ? -1.0f : 0.0f;
  __syncthreads();
  float4* ob = (float4*)(out + TOPK);
  for (int i = tid; i < MM; i += 256) {
    int cc = i >> 6, b = i & 63;
    u64 kb = keepw[cc];
    if ((kb >> b) & 1ull) {
      int rank = pref[cc] + __popcll(kb & ((1ull << b) - 1ull));
      if (rank < TOPK) {
        out[rank] = ssc[i];
        ob[rank] = sboxes[i];
      }
    }
  }
}

extern "C" void kernel_launch(void* const* d_in, const int* in_sizes, int n_in,
                              void* d_out, int out_size, void* d_ws, size_t ws_size,
                              hipStream_t stream) {
  const float* x  = (const float*)d_in[0];
  const float* cw = (const float*)d_in[1];
  const float* cb = (const float*)d_in[2];
  const float* dw = (const float*)d_in[3];
  const float* db = (const float*)d_in[4];
  const float* rw = (const float*)d_in[5];
  const float* rb = (const float*)d_in[6];
  const float* an = (const float*)d_in[7];
  char* ws = (char*)d_ws;
  float*  interp = (float*)(ws);                 // 4,718,592 B
  float*  s      = (float*)(ws + 4718592);       // 27,648 B
  float4* boxes  = (float4*)(ws + 4746240);      // 110,592 B
  float*  ssc    = (float*)(ws + 4856832);       // 27,648 B
  float4* sboxes = (float4*)(ws + 4884480);      // 110,592 B
  u64*    mask   = (u64*)(ws + 4995072);         // 5,971,968 B
  u64*    nz     = (u64*)(ws + 10967040);        // 110,592 B
  float* out = (float*)d_out;

  hipLaunchKernelGGL(k_conv, dim3(4, 48, 2), dim3(256), 0, stream, x, cw, interp);
  hipLaunchKernelGGL(k_decode, dim3(9), dim3(256), 0, stream, interp, cb, dw, db, rw, rb, an, s, boxes);
  hipLaunchKernelGGL(k_zero, dim3(54), dim3(256), 0, stream, nz);
  hipLaunchKernelGGL(k_sort, dim3(1), dim3(1024), 0, stream, s, boxes, ssc, sboxes);
  hipLaunchKernelGGL(k_mask, dim3(108, 27), dim3(256), 0, stream, sboxes, mask, nz);
  hipLaunchKernelGGL(k_scan, dim3(1), dim3(256), 0, stream, mask, nz, ssc, sboxes, out);
}

// Round 3
// 315.665 us; speedup vs baseline: 2.7814x; 1.4283x over previous
//
#include <hip/hip_runtime.h>
#include <cstdint>

#define NPX 2304      // 48*48
#define MM 6912       // 3*2304
#define NW 108        // MM/64
#define TOPK 2000
#define NEGV -1000000000.0f
#define OBJ_THRF 0.3f
#define IOU_THRF 0.7f
#define IMGF 768.0f

typedef unsigned long long u64;
typedef unsigned int u32;

__device__ __forceinline__ u64 shfl64(u64 v, int src) {
  int lo = __shfl((int)(v & 0xffffffffull), src, 64);
  int hi = __shfl((int)(v >> 32), src, 64);
  return ((u64)(u32)hi << 32) | (u32)lo;
}

// ---------------- conv 3x3, 256->256, fp32 ----------------
__global__ __launch_bounds__(256) void k_conv(const float* __restrict__ x,
                                              const float* __restrict__ cw,
                                              float* __restrict__ interp) {
  __shared__ float xs[16 * 3 * 50];    // [ic][row][col+1], zero-padded halo
  __shared__ float wl[144 * 66];       // [it = ic*9+tap][oc], stride 66
  const int tid = threadIdx.x;
  const int og = tid & 15;             // oc group: oc = oc0 + og*4 + kk
  const int pg = tid >> 4;             // px group: px = 3*pg + p
  const int oc0 = blockIdx.x * 64;
  const int h = blockIdx.y;
  const int ks = blockIdx.z;

  float acc[4][3];
#pragma unroll
  for (int i = 0; i < 4; i++)
#pragma unroll
    for (int j = 0; j < 3; j++) acc[i][j] = 0.f;

  for (int icc = 0; icc < 8; ++icc) {
    const int ic0 = ks * 128 + icc * 16;
    for (int e = tid; e < 2400; e += 256) {
      int ic = e / 150, rem = e % 150;
      int r = rem / 50, col = rem % 50 - 1;
      int gr = h - 1 + r;
      float v = 0.f;
      if (col >= 0 && col < 48 && gr >= 0 && gr < 48)
        v = x[(ic0 + ic) * NPX + gr * 48 + col];
      xs[e] = v;
    }
    for (int e = tid; e < 9216; e += 256) {
      int oc = e / 144, it = e % 144;
      wl[it * 66 + oc] = cw[(oc0 + oc) * 2304 + ic0 * 9 + it];
    }
    __syncthreads();
#pragma unroll
    for (int ic = 0; ic < 16; ++ic) {
      float xr[3][5];
#pragma unroll
      for (int r = 0; r < 3; r++)
#pragma unroll
        for (int q = 0; q < 5; q++)
          xr[r][q] = xs[(ic * 3 + r) * 50 + 3 * pg + q];
#pragma unroll
      for (int r = 0; r < 3; r++)
#pragma unroll
        for (int dxk = 0; dxk < 3; dxk++) {
          int it = ic * 9 + r * 3 + dxk;
          const float2 w01 = *(const float2*)&wl[it * 66 + og * 4];
          const float2 w23 = *(const float2*)&wl[it * 66 + og * 4 + 2];
          float wv[4] = {w01.x, w01.y, w23.x, w23.y};
#pragma unroll
          for (int p = 0; p < 3; p++) {
            float xv = xr[r][p + dxk];
#pragma unroll
            for (int kk = 0; kk < 4; kk++) acc[kk][p] += wv[kk] * xv;
          }
        }
    }
    __syncthreads();
  }
#pragma unroll
  for (int kk = 0; kk < 4; kk++) {
    int oc = oc0 + og * 4 + kk;
#pragma unroll
    for (int p = 0; p < 3; p++)
      interp[ks * (256 * NPX) + oc * NPX + h * 48 + 3 * pg + p] = acc[kk][p];
  }
}

// ---------------- heads + anchor decode ----------------
__global__ __launch_bounds__(256) void k_decode(const float* __restrict__ interp,
                                                const float* __restrict__ cb,
                                                const float* __restrict__ dw,
                                                const float* __restrict__ db,
                                                const float* __restrict__ rw,
                                                const float* __restrict__ rb,
                                                const float* __restrict__ anch,
                                                float* __restrict__ s,
                                                float4* __restrict__ boxes) {
  __shared__ float wl[256 * 16];
  const int tid = threadIdx.x;
  const int p = blockIdx.x * 256 + tid;
  for (int e = tid; e < 3840; e += 256) {
    int o = e % 15, c = e / 15;
    wl[c * 16 + o] = (o < 3) ? dw[o * 256 + c] : rw[(o - 3) * 256 + c];
  }
  __syncthreads();
  float acc[15];
#pragma unroll
  for (int o = 0; o < 15; o++) acc[o] = 0.f;
  const float* p0 = interp;
  const float* p1 = interp + 256 * NPX;
  for (int c = 0; c < 256; ++c) {
    float v = p0[c * NPX + p] + p1[c * NPX + p] + cb[c];
#pragma unroll
    for (int o = 0; o < 15; o++) acc[o] += v * wl[c * 16 + o];
  }
  const float4* an4 = (const float4*)anch;
#pragma unroll
  for (int a = 0; a < 3; ++a) {
    int m = a * NPX + p;
    float logit = acc[a] + db[a];
    float score = 1.f / (1.f + expf(-logit));
    float dxv = acc[3 + 0 + a] + rb[0 + a];
    float dyv = acc[3 + 3 + a] + rb[3 + a];
    float dwv = acc[3 + 6 + a] + rb[6 + a];
    float dhv = acc[3 + 9 + a] + rb[9 + a];
    float4 an = an4[m];
    float aw = an.z - an.x;
    float ah = an.w - an.y;
    float acx = an.y + aw * 0.5f;  // NOTE: intentionally swapped (reference quirk)
    float acy = an.x + ah * 0.5f;  // NOTE: intentionally swapped (reference quirk)
    float pxc = acx + dxv * aw;
    float pyc = acy + dyv * ah;
    float pw = aw * expf(dwv);
    float ph = ah * expf(dhv);
    float b0 = pxc - pw * 0.5f, b1 = pyc - ph * 0.5f;
    float b2 = pxc + pw * 0.5f, b3 = pyc + ph * 0.5f;
    b0 = fminf(fmaxf(b0, 0.f), IMGF);
    b1 = fminf(fmaxf(b1, 0.f), IMGF);
    b2 = fminf(fmaxf(b2, 0.f), IMGF);
    b3 = fminf(fmaxf(b3, 0.f), IMGF);
    float hts = b2 - b0, wds = b3 - b1;
    bool valid = (hts > 0.f) && (wds > 0.f) && (score > OBJ_THRF);
    s[m] = valid ? score : NEGV;
    boxes[m] = make_float4(b0, b1, b2, b3);
  }
}

// ---------------- sort phase 1: 8 blocks x 1024-elem bitonic runs ----------
// key = (~monotone_u32(score)) << 32 | idx  → ascending u64 == descending
// score, idx-ascending tie-break. All keys distinct (idx in low bits).
__global__ __launch_bounds__(256) void k_sortA(const float* __restrict__ s,
                                               u64* __restrict__ keys) {
  __shared__ u64 lds[1024];
  const int tid = threadIdx.x;
  const int b = blockIdx.x;
  for (int v = tid; v < 1024; v += 256) {
    int i = b * 1024 + v;
    u64 p;
    if (i < MM) {
      u32 u = __float_as_uint(s[i]);
      u = u ^ (u32)(((int)u >> 31) | 0x80000000);
      p = ((u64)(~u) << 32) | (u32)i;
    } else {
      p = ~0ull;  // pad sorts last (real keys have high word < 0xFFFFFFFF)
    }
    lds[v] = p;
  }
  for (u32 kk = 2; kk <= 1024; kk <<= 1) {
    for (u32 j = kk >> 1; j > 0; j >>= 1) {
      __syncthreads();
#pragma unroll 2
      for (int t = tid; t < 512; t += 256) {
        int i = ((t & ~(j - 1)) << 1) | (t & (j - 1));
        int l = i | j;
        bool up = ((i & kk) == 0);
        u64 a = lds[i], c = lds[l];
        u64 mn = a < c ? a : c;
        u64 mx = a < c ? c : a;
        lds[i] = up ? mn : mx;
        lds[l] = up ? mx : mn;
      }
    }
  }
  __syncthreads();
  for (int v = tid; v < 1024; v += 256) keys[b * 1024 + v] = lds[v];
}

// ---------------- sort phase 2: merge-path rounds ----------------
// merges pairs of ascending runs of length L; one output element per thread.
// fin!=0 on the last round also gathers ssc/sboxes.
__global__ __launch_bounds__(256) void k_merge(const u64* __restrict__ in,
                                               u64* __restrict__ outk, int L, int fin,
                                               const float* __restrict__ s,
                                               const float4* __restrict__ boxes,
                                               float* __restrict__ ssc,
                                               float4* __restrict__ sboxes) {
  const int i = blockIdx.x * 256 + threadIdx.x;  // 0..8191
  const int pair = i / (2 * L);
  const int r = i - pair * 2 * L;
  const u64* A = in + (size_t)pair * 2 * L;
  const u64* B = A + L;
  int lo = (r > L) ? (r - L) : 0;
  int hi = (r < L) ? r : L;
  while (lo < hi) {
    int mid = (lo + hi) >> 1;
    if (A[mid] < B[r - 1 - mid]) lo = mid + 1; else hi = mid;
  }
  int a = lo, bi = r - lo;
  u64 av = (a < L) ? A[a] : ~0ull;
  u64 bv = (bi < L) ? B[bi] : ~0ull;
  u64 o = (av < bv) ? av : bv;
  outk[i] = o;
  if (fin && i < MM) {
    int idx = (int)(u32)o;
    ssc[i] = s[idx];
    sboxes[i] = boxes[idx];
  }
}

// ---------------- zero-init nz bitmaps ----------------
__global__ __launch_bounds__(256) void k_zero(u64* __restrict__ nz) {
  int i = blockIdx.x * 256 + threadIdx.x;
  if (i < MM * 2) nz[i] = 0;
}

// ---------------- IOU suppression bit-matrix (transposed) ----------------
__global__ __launch_bounds__(256) void k_mask(const float4* __restrict__ sboxes,
                                              u64* __restrict__ mask_t,
                                              u64* __restrict__ nz) {
  __shared__ float4 rb_[64];
  const int rt = blockIdx.x;
  const int w = blockIdx.y * 4 + (threadIdx.x >> 6);
  const int lane = threadIdx.x & 63;
  if (threadIdx.x < 64) rb_[threadIdx.x] = sboxes[rt * 64 + threadIdx.x];
  __syncthreads();
  if (w < rt) return;  // only words >= diagonal are ever read
  float4 c = sboxes[w * 64 + lane];
  float areaC = (c.z - c.x) * (c.w - c.y);
  u64 myw = 0;
  for (int r = 0; r < 64; ++r) {
    float4 b = rb_[r];
    float iw = fmaxf(fminf(b.z, c.z) - fmaxf(b.x, c.x), 0.f);
    float ih = fmaxf(fminf(b.w, c.w) - fmaxf(b.y, c.y), 0.f);
    float inter = iw * ih;
    float areaB = (b.z - b.x) * (b.w - b.y);
    float un = fmaxf(areaB + areaC - inter, 1e-9f);
    bool bit = (inter / un) > IOU_THRF;
    u64 bal = __ballot(bit);
    if (lane == r) myw = bal;
  }
  mask_t[(size_t)w * MM + rt * 64 + lane] = myw;  // coalesced
  if (myw) atomicOr(&nz[(rt * 64 + lane) * 2 + (w >> 6)], 1ull << (w & 63));
}

// ---------------- serial NMS scan + output ----------------
__global__ __launch_bounds__(256) void k_scan(const u64* __restrict__ mask_t,
                                              const u64* __restrict__ nz,
                                              const float* __restrict__ ssc,
                                              const float4* __restrict__ sboxes,
                                              float* __restrict__ out) {
  __shared__ u64 remv[NW];
  __shared__ u64 keepw[NW];
  __shared__ int blist[64];
  __shared__ int nkS;
  __shared__ int kcntS;
  __shared__ int pref[NW];
  const int tid = threadIdx.x;
  if (tid < NW) { remv[tid] = 0; keepw[tid] = 0; }
  if (tid == 0) kcntS = 0;
  __syncthreads();

  for (int c = 0; c < NW; ++c) {
    if (tid < 64) {  // wave 0
      const int lane = tid;
      u64 dg = mask_t[(size_t)c * MM + c * 64 + lane];  // coalesced 512B
      float sv = ssc[c * 64 + lane];
      u64 vb = __ballot(sv > OBJ_THRF);
      u64 w0 = remv[c];
      u64 cand = vb & ~w0;
      u64 above = (lane < 63) ? ~((2ull << lane) - 1ull) : 0ull;
      bool inC = ((cand >> lane) & 1ull) != 0;
      u64 conf = __ballot(inC && ((dg & above & cand) != 0ull));
      u64 kb;
      if (conf == 0ull) {
        kb = cand;  // fast path: no intra-chunk suppression among candidates
      } else {
        u64 w = w0;
        kb = 0;
        u64 rem = cand;
        while (rem) {
          int b = __ffsll(rem) - 1;
          kb |= (1ull << b);
          w |= shfl64(dg, b);
          rem = vb & ~w;
        }
      }
      int below = __popcll(kb & ((1ull << lane) - 1ull));
      if ((kb >> lane) & 1ull) blist[below] = lane;
      if (lane == 0) {
        keepw[c] = kb;
        nkS = __popcll(kb);
        kcntS += __popcll(kb);
      }
    }
    __syncthreads();
    int nk = nkS;
    if (tid < nk) {  // sparse propagation: only nonzero words > c
      int row = c * 64 + blist[tid];
      u64 nz0 = nz[row * 2], nz1 = nz[row * 2 + 1];
      if (c < 64) {
        nz0 &= (c < 63) ? ~((2ull << c) - 1ull) : 0ull;
      } else {
        nz0 = 0;
        int cc = c - 64;
        nz1 &= ~((2ull << cc) - 1ull);
      }
      while (nz0) {
        int wv = __ffsll(nz0) - 1; nz0 &= nz0 - 1;
        atomicOr(&remv[wv], mask_t[(size_t)wv * MM + row]);
      }
      while (nz1) {
        int wv = __ffsll(nz1) - 1; nz1 &= nz1 - 1;
        atomicOr(&remv[wv + 64], mask_t[(size_t)(wv + 64) * MM + row]);
      }
    }
    __syncthreads();
    if (kcntS >= TOPK) break;  // only top-2000 kept are ever output
  }

  if (tid == 0) {
    int run = 0;
    for (int cc = 0; cc < NW; ++cc) { pref[cc] = run; run += __popcll(keepw[cc]); }
  }
  __syncthreads();
  for (int e = tid; e < TOPK * 5; e += 256) out[e] = (e < TOPK) ? -1.0f : 0.0f;
  __syncthreads();
  float4* ob = (float4*)(out + TOPK);
  for (int i = tid; i < MM; i += 256) {
    int cc = i >> 6, b = i & 63;
    u64 kb = keepw[cc];
    if ((kb >> b) & 1ull) {
      int rank = pref[cc] + __popcll(kb & ((1ull << b) - 1ull));
      if (rank < TOPK) {
        out[rank] = ssc[i];
        ob[rank] = sboxes[i];
      }
    }
  }
}

extern "C" void kernel_launch(void* const* d_in, const int* in_sizes, int n_in,
                              void* d_out, int out_size, void* d_ws, size_t ws_size,
                              hipStream_t stream) {
  const float* x  = (const float*)d_in[0];
  const float* cw = (const float*)d_in[1];
  const float* cb = (const float*)d_in[2];
  const float* dw = (const float*)d_in[3];
  const float* db = (const float*)d_in[4];
  const float* rw = (const float*)d_in[5];
  const float* rb = (const float*)d_in[6];
  const float* an = (const float*)d_in[7];
  char* ws = (char*)d_ws;
  float*  interp = (float*)(ws);                 // 4,718,592 B (dead after k_decode)
  u64*    keysA  = (u64*)(ws);                   // 65,536 B — aliases interp (safe)
  u64*    keysB  = (u64*)(ws + 65536);           // 65,536 B — aliases interp (safe)
  float*  s      = (float*)(ws + 4718592);       // 27,648 B
  float4* boxes  = (float4*)(ws + 4746240);      // 110,592 B
  float*  ssc    = (float*)(ws + 4856832);       // 27,648 B
  float4* sboxes = (float4*)(ws + 4884480);      // 110,592 B
  u64*    mask   = (u64*)(ws + 4995072);         // 5,971,968 B
  u64*    nz     = (u64*)(ws + 10967040);        // 110,592 B
  float* out = (float*)d_out;

  hipLaunchKernelGGL(k_conv, dim3(4, 48, 2), dim3(256), 0, stream, x, cw, interp);
  hipLaunchKernelGGL(k_decode, dim3(9), dim3(256), 0, stream, interp, cb, dw, db, rw, rb, an, s, boxes);
  hipLaunchKernelGGL(k_zero, dim3(54), dim3(256), 0, stream, nz);
  hipLaunchKernelGGL(k_sortA, dim3(8), dim3(256), 0, stream, s, keysA);
  hipLaunchKernelGGL(k_merge, dim3(32), dim3(256), 0, stream, keysA, keysB, 1024, 0, s, boxes, ssc, sboxes);
  hipLaunchKernelGGL(k_merge, dim3(32), dim3(256), 0, stream, keysB, keysA, 2048, 0, s, boxes, ssc, sboxes);
  hipLaunchKernelGGL(k_merge, dim3(32), dim3(256), 0, stream, keysA, keysB, 4096, 1, s, boxes, ssc, sboxes);
  hipLaunchKernelGGL(k_mask, dim3(108, 27), dim3(256), 0, stream, sboxes, mask, nz);
  hipLaunchKernelGGL(k_scan, dim3(1), dim3(256), 0, stream, mask, nz, ssc, sboxes, out);
}